// Round 7
// baseline (489.573 us; speedup 1.0000x reference)
//
#include <hip/hip_runtime.h>
#include <hip/hip_fp16.h>

// N=100000 nodes, E=1000000 edges, D_IN=16, H=2, C=64.
// 3x (GAT -> BN -> ReLU), then MLP head -> (logits, value) concat in d_out.
// R25: aggregate main loop widened 4 -> 8 edges/iteration (R24 counters:
// 3.56 TB/s = 55% of achievable, VALUBusy 41%, occupancy 63% -> latency-bound
// on the gather chain; double the rows in flight). 32-bit byte-offset
// addressing for hb/as_ (kills 64-bit addr math on the gather path).
// Kept: R24 16-lanes/node 4-nodes/wave layout (59.5->46.3us), int col CSR,
// NT out stores, separate slice-write bn_stats (fused atomics cost ~50us,
// R22), R17 CSR build, scsh BN fusion into consumers.

__device__ __forceinline__ float leaky(float x) { return x > 0.f ? x : 0.2f * x; }

typedef float f32x4 __attribute__((ext_vector_type(4)));

#define BCAP 4096  // max edges per 256-dst bucket (mean ~2560)
#define NSL 256    // bn_stats slices

// ---------------- CSR build ----------------
__global__ void bucket_hist(const int* __restrict__ dst, int* __restrict__ bcnt, int E) {
  __shared__ int cnt[512];
  int t = threadIdx.x;
  cnt[t] = 0; cnt[t + 256] = 0;
  __syncthreads();
  for (int e = blockIdx.x * blockDim.x + t; e < E; e += gridDim.x * blockDim.x)
    atomicAdd(&cnt[dst[e] >> 8], 1);
  __syncthreads();
  for (int i = t; i < 512; i += 256)
    if (cnt[i]) atomicAdd(&bcnt[i], cnt[i]);
}

__global__ void bucket_scan(const int* __restrict__ bcnt, int* __restrict__ boff,
                            int* __restrict__ bcur, int nbk) {
  __shared__ int temp[512];
  int t = threadIdx.x;  // 512 threads
  int v = (t < nbk) ? bcnt[t] : 0;
  temp[t] = v;
  __syncthreads();
  for (int off = 1; off < 512; off <<= 1) {
    int add = (t >= off) ? temp[t - off] : 0;
    __syncthreads();
    temp[t] += add;
    __syncthreads();
  }
  if (t < nbk) {
    int ex = temp[t] - v;
    boff[t] = ex;
    bcur[t] = ex;
  }
}

__global__ __launch_bounds__(256) void bin_scatter(
    const int* __restrict__ src, const int* __restrict__ dst,
    int* __restrict__ bcur, int2* __restrict__ ebuf, int E) {
  __shared__ int cnt[512];
  __shared__ int base[512];
  int t = threadIdx.x;
  int beg = blockIdx.x * 8192;
  int end = min(E, beg + 8192);
  cnt[t] = 0; cnt[t + 256] = 0;
  __syncthreads();
  for (int e = beg + t; e < end; e += 256)
    atomicAdd(&cnt[dst[e] >> 8], 1);
  __syncthreads();
  for (int i = t; i < 512; i += 256) {
    base[i] = cnt[i] ? atomicAdd(&bcur[i], cnt[i]) : 0;
    cnt[i] = 0;  // reuse as within-run cursor
  }
  __syncthreads();
  for (int e = beg + t; e < end; e += 256) {
    int d = dst[e];
    int bk = d >> 8;
    int off = atomicAdd(&cnt[bk], 1);
    ebuf[base[bk] + off] = make_int2(src[e], d);
  }
}

__global__ __launch_bounds__(256) void bucket_sort(
    const int2* __restrict__ ebuf, const int* __restrict__ boff,
    int* __restrict__ col, int* __restrict__ row_ptr, int E, int n, int nbk) {
  __shared__ int2 eds[BCAP];
  __shared__ int dcnt[256];
  __shared__ int dbase[256];
  __shared__ int dexcl[256];
  int b = blockIdx.x, t = threadIdx.x;
  int S = boff[b];
  int Eend = (b + 1 < nbk) ? boff[b + 1] : E;
  int cnt = min(Eend - S, BCAP);
  for (int i = t; i < cnt; i += 256) eds[i] = ebuf[S + i];
  dcnt[t] = 0;
  __syncthreads();
  for (int i = t; i < cnt; i += 256) atomicAdd(&dcnt[eds[i].y & 255], 1);
  __syncthreads();
  int v = dcnt[t];
  dbase[t] = v;
  __syncthreads();
  for (int off = 1; off < 256; off <<= 1) {
    int add = (t >= off) ? dbase[t - off] : 0;
    __syncthreads();
    dbase[t] += add;
    __syncthreads();
  }
  int excl = dbase[t] - v;
  int d = (b << 8) + t;
  if (d < n) row_ptr[d] = S + excl;
  if (b == nbk - 1 && t == 0) row_ptr[n] = E;
  dcnt[t] = 0;  // reuse as per-dst cursor
  dexcl[t] = excl;
  __syncthreads();
  for (int i = t; i < cnt; i += 256) {
    int2 e = eds[i];
    int dl = e.y & 255;
    int off = atomicAdd(&dcnt[dl], 1);
    col[S + dexcl[dl] + off] = e.x;
  }
}

// ---------------- BN stats (vectorized, slice writes) + finalize ----------
__global__ __launch_bounds__(256) void bn_stats(const float* __restrict__ h,
                                                float* __restrict__ stats, int n) {
  __shared__ float ssum[64], ssq[64];
  int t = threadIdx.x;
  if (t < 64) { ssum[t] = 0.f; ssq[t] = 0.f; }
  __syncthreads();
  const float4* h4 = (const float4*)h;
  size_t total4 = (size_t)n * 16;
  size_t stride = (size_t)gridDim.x * blockDim.x;   // multiple of 16
  int cbase = ((int)(((size_t)blockIdx.x * blockDim.x + t) & 15)) * 4;
  float s0 = 0.f, s1 = 0.f, s2 = 0.f, s3 = 0.f;
  float q0 = 0.f, q1 = 0.f, q2 = 0.f, q3 = 0.f;
  for (size_t i = (size_t)blockIdx.x * blockDim.x + t; i < total4; i += stride) {
    float4 v = h4[i];
    s0 += v.x; q0 = fmaf(v.x, v.x, q0);
    s1 += v.y; q1 = fmaf(v.y, v.y, q1);
    s2 += v.z; q2 = fmaf(v.z, v.z, q2);
    s3 += v.w; q3 = fmaf(v.w, v.w, q3);
  }
  atomicAdd(&ssum[cbase + 0], s0); atomicAdd(&ssq[cbase + 0], q0);
  atomicAdd(&ssum[cbase + 1], s1); atomicAdd(&ssq[cbase + 1], q1);
  atomicAdd(&ssum[cbase + 2], s2); atomicAdd(&ssq[cbase + 2], q2);
  atomicAdd(&ssum[cbase + 3], s3); atomicAdd(&ssq[cbase + 3], q3);
  __syncthreads();
  if (t < 64) {
    stats[blockIdx.x * 128 + t] = ssum[t];
    stats[blockIdx.x * 128 + 64 + t] = ssq[t];
  }
}

// reduce NSL slices -> scsh (scale/shift). 128 threads: t<64 sums, else sumsq.
__global__ void bn_finalize(const float* __restrict__ stats, const float* __restrict__ g,
                            const float* __restrict__ be, float* __restrict__ scsh,
                            float inv_n) {
  __shared__ float red[128];
  int t = threadIdx.x;  // 128
  int c = t & 63;
  int off = (t >> 6) * 64;  // 0 = sum, 64 = sumsq
  float acc = 0.f;
  for (int b = 0; b < NSL; b++) acc += stats[b * 128 + off + c];
  red[t] = acc;
  __syncthreads();
  if (t < 64) {
    float mean = red[t] * inv_n;
    float var = red[64 + t] * inv_n - mean * mean;
    float sc = rsqrtf(var + 1e-5f) * g[t];
    scsh[t] = sc;
    scsh[64 + t] = be[t] - mean * sc;
  }
}

// ---------------- GAT projection: LDS-tiled GEMM, 64 nodes x 128 cols -------
// h = act @ W (BN+ReLU fused into A-staging when BN=true).
template <int K, bool BN>
__global__ __launch_bounds__(256) void gat_project_tiled(
    const float* __restrict__ act, const float* __restrict__ scsh,
    const float* __restrict__ W,
    const float* __restrict__ att_s, const float* __restrict__ att_d,
    __half2* __restrict__ hb, float* __restrict__ as_,
    float* __restrict__ ad_, int n) {
  constexpr int AST = K + 4;
  __shared__ float aS[64 * AST];
  __shared__ float wS[K * 128];
  __shared__ float attS[256];

  int t = threadIdx.x;
  int node0 = blockIdx.x * 64;
  int rows = min(64, n - node0);

  constexpr int AF4 = 64 * K / 4;
  for (int i = t; i < AF4; i += 256) {
    int r = i / (K / 4), kc = i % (K / 4);
    float4 v = make_float4(0.f, 0.f, 0.f, 0.f);
    if (r < rows) v = *(const float4*)&act[(size_t)(node0 + r) * K + kc * 4];
    if (BN) {
      float4 sc4 = *(const float4*)&scsh[kc * 4];
      float4 sh4 = *(const float4*)&scsh[64 + kc * 4];
      v.x = fmaxf(fmaf(v.x, sc4.x, sh4.x), 0.f);
      v.y = fmaxf(fmaf(v.y, sc4.y, sh4.y), 0.f);
      v.z = fmaxf(fmaf(v.z, sc4.z, sh4.z), 0.f);
      v.w = fmaxf(fmaf(v.w, sc4.w, sh4.w), 0.f);
    }
    *(float4*)&aS[r * AST + kc * 4] = v;
  }
  constexpr int WF4 = K * 32;
  for (int i = t; i < WF4; i += 256)
    *(float4*)&wS[i * 4] = *(const float4*)&W[i * 4];
  attS[t] = (t < 128) ? att_s[t] : att_d[t - 128];
  __syncthreads();

  int tc = t & 15, tr = t >> 4;
  int c0 = tc * 8, r0 = tr * 4;

  float acc[4][8] = {};
  for (int k = 0; k < K; k += 4) {
    float4 av[4];
    float4 wv[4][2];
#pragma unroll
    for (int i = 0; i < 4; i++) av[i] = *(const float4*)&aS[(r0 + i) * AST + k];
#pragma unroll
    for (int kk = 0; kk < 4; kk++) {
      wv[kk][0] = *(const float4*)&wS[(k + kk) * 128 + c0];
      wv[kk][1] = *(const float4*)&wS[(k + kk) * 128 + c0 + 4];
    }
#pragma unroll
    for (int i = 0; i < 4; i++) {
      const float* ai = (const float*)&av[i];
#pragma unroll
      for (int kk = 0; kk < 4; kk++) {
        const float* w0 = (const float*)&wv[kk][0];
        const float* w1 = (const float*)&wv[kk][1];
#pragma unroll
        for (int j = 0; j < 4; j++) {
          acc[i][j] = fmaf(ai[kk], w0[j], acc[i][j]);
          acc[i][4 + j] = fmaf(ai[kk], w1[j], acc[i][4 + j]);
        }
      }
    }
  }

#pragma unroll
  for (int i = 0; i < 4; i++) {
    int r = r0 + i;
    float psv = 0.f, pdv = 0.f;
#pragma unroll
    for (int j = 0; j < 8; j++) {
      psv = fmaf(acc[i][j], attS[c0 + j], psv);
      pdv = fmaf(acc[i][j], attS[128 + c0 + j], pdv);
    }
    psv += __shfl_xor(psv, 1); pdv += __shfl_xor(pdv, 1);
    psv += __shfl_xor(psv, 2); pdv += __shfl_xor(pdv, 2);
    psv += __shfl_xor(psv, 4); pdv += __shfl_xor(pdv, 4);
    if (r < rows) {
      size_t base = (size_t)(node0 + r) * 64 + (c0 >> 1);
      hb[base + 0] = __floats2half2_rn(acc[i][0], acc[i][1]);
      hb[base + 1] = __floats2half2_rn(acc[i][2], acc[i][3]);
      hb[base + 2] = __floats2half2_rn(acc[i][4], acc[i][5]);
      hb[base + 3] = __floats2half2_rn(acc[i][6], acc[i][7]);
      if (tc == 0 || tc == 8) {
        int head = tc >> 3;
        as_[(node0 + r) * 2 + head] = psv;
        ad_[(node0 + r) * 2 + head] = pdv;
      }
    }
  }
}

// ---------------- GAT aggregation: 16 lanes/node, 4 nodes/wave ---------------
// Lane q accumulates its 8 channels of head (q>=8) over ALL edges of its
// node. Main loop 8 edges/iter: 8 col + 8 as_ + 8 hb(256B) loads issued
// before consumption -> 32 rows in flight per wave. 32-bit byte offsets.
__device__ __forceinline__ void fma8(float* a, float my, uint4 raw) {
  float2 f;
  f = __half22float2(__builtin_bit_cast(__half2, raw.x)); a[0] = fmaf(my, f.x, a[0]); a[1] = fmaf(my, f.y, a[1]);
  f = __half22float2(__builtin_bit_cast(__half2, raw.y)); a[2] = fmaf(my, f.x, a[2]); a[3] = fmaf(my, f.y, a[3]);
  f = __half22float2(__builtin_bit_cast(__half2, raw.z)); a[4] = fmaf(my, f.x, a[4]); a[5] = fmaf(my, f.y, a[5]);
  f = __half22float2(__builtin_bit_cast(__half2, raw.w)); a[6] = fmaf(my, f.x, a[6]); a[7] = fmaf(my, f.y, a[7]);
}

__global__ __launch_bounds__(256, 4) void gat_aggregate(
    const __half2* __restrict__ hb,
    const float* __restrict__ as_, const float* __restrict__ ad_,
    const int* __restrict__ row_ptr, const int* __restrict__ col,
    const float* __restrict__ bias, float* __restrict__ out, int n) {
  int w = (int)((blockIdx.x * blockDim.x + threadIdx.x) >> 6);
  int lane = threadIdx.x & 63;
  int g = lane >> 4, q = lane & 15;
  int d = w * 4 + g;
  if (d >= n) return;  // diverges only in the last wave
  int hidx = (q >= 8) ? 1 : 0;
  int beg = row_ptr[d], end = row_ptr[d + 1];
  const char* hbp = (const char*)hb;       // 256 B per node row
  const char* asp = (const char*)as_;      // 8 B per node
  unsigned hoff = (unsigned)(hidx << 2);
  unsigned qoff = (unsigned)(q << 4);

  float ad_my = *(const float*)(asp + ((unsigned)(ad_ - as_) * 4u) + ((unsigned)d << 3) + hoff);
  // (ad_ is laid out right after as_ in the workspace; compute via its own ptr
  //  to stay safe w.r.t. aliasing instead:)
  ad_my = ad_[d * 2 + hidx];

  float a[8] = {};
  // self-loop (not in CSR)
  float asv = *(const float*)(asp + ((unsigned)d << 3) + hoff);
  float my = __expf(leaky(asv + ad_my));
  uint4 raw = *(const uint4*)(hbp + ((unsigned)d << 8) + qoff);
  fma8(a, my, raw);
  float dpart = my;

  int k = beg;
  // main: 8 edges per iteration, all 16 gathers issued before consumption
  for (; k + 7 < end; k += 8) {
    int s0 = col[k],     s1 = col[k + 1], s2 = col[k + 2], s3 = col[k + 3];
    int s4 = col[k + 4], s5 = col[k + 5], s6 = col[k + 6], s7 = col[k + 7];
    float e0 = *(const float*)(asp + ((unsigned)s0 << 3) + hoff);
    float e1 = *(const float*)(asp + ((unsigned)s1 << 3) + hoff);
    float e2 = *(const float*)(asp + ((unsigned)s2 << 3) + hoff);
    float e3 = *(const float*)(asp + ((unsigned)s3 << 3) + hoff);
    float e4 = *(const float*)(asp + ((unsigned)s4 << 3) + hoff);
    float e5 = *(const float*)(asp + ((unsigned)s5 << 3) + hoff);
    float e6 = *(const float*)(asp + ((unsigned)s6 << 3) + hoff);
    float e7 = *(const float*)(asp + ((unsigned)s7 << 3) + hoff);
    uint4 r0 = *(const uint4*)(hbp + ((unsigned)s0 << 8) + qoff);
    uint4 r1 = *(const uint4*)(hbp + ((unsigned)s1 << 8) + qoff);
    uint4 r2 = *(const uint4*)(hbp + ((unsigned)s2 << 8) + qoff);
    uint4 r3 = *(const uint4*)(hbp + ((unsigned)s3 << 8) + qoff);
    uint4 r4 = *(const uint4*)(hbp + ((unsigned)s4 << 8) + qoff);
    uint4 r5 = *(const uint4*)(hbp + ((unsigned)s5 << 8) + qoff);
    uint4 r6 = *(const uint4*)(hbp + ((unsigned)s6 << 8) + qoff);
    uint4 r7 = *(const uint4*)(hbp + ((unsigned)s7 << 8) + qoff);
    float m0 = __expf(leaky(e0 + ad_my));
    float m1 = __expf(leaky(e1 + ad_my));
    float m2 = __expf(leaky(e2 + ad_my));
    float m3 = __expf(leaky(e3 + ad_my));
    float m4 = __expf(leaky(e4 + ad_my));
    float m5 = __expf(leaky(e5 + ad_my));
    float m6 = __expf(leaky(e6 + ad_my));
    float m7 = __expf(leaky(e7 + ad_my));
    fma8(a, m0, r0); fma8(a, m1, r1); fma8(a, m2, r2); fma8(a, m3, r3);
    fma8(a, m4, r4); fma8(a, m5, r5); fma8(a, m6, r6); fma8(a, m7, r7);
    dpart += ((m0 + m1) + (m2 + m3)) + ((m4 + m5) + (m6 + m7));
  }
  if (k + 3 < end) {  // 4-tail
    int s0 = col[k], s1 = col[k + 1], s2 = col[k + 2], s3 = col[k + 3];
    float e0 = *(const float*)(asp + ((unsigned)s0 << 3) + hoff);
    float e1 = *(const float*)(asp + ((unsigned)s1 << 3) + hoff);
    float e2 = *(const float*)(asp + ((unsigned)s2 << 3) + hoff);
    float e3 = *(const float*)(asp + ((unsigned)s3 << 3) + hoff);
    uint4 r0 = *(const uint4*)(hbp + ((unsigned)s0 << 8) + qoff);
    uint4 r1 = *(const uint4*)(hbp + ((unsigned)s1 << 8) + qoff);
    uint4 r2 = *(const uint4*)(hbp + ((unsigned)s2 << 8) + qoff);
    uint4 r3 = *(const uint4*)(hbp + ((unsigned)s3 << 8) + qoff);
    float m0 = __expf(leaky(e0 + ad_my));
    float m1 = __expf(leaky(e1 + ad_my));
    float m2 = __expf(leaky(e2 + ad_my));
    float m3 = __expf(leaky(e3 + ad_my));
    fma8(a, m0, r0); fma8(a, m1, r1); fma8(a, m2, r2); fma8(a, m3, r3);
    dpart += (m0 + m1) + (m2 + m3);
    k += 4;
  }
  for (; k < end; k++) {  // scalar tail 0..3
    int s = col[k];
    float e = *(const float*)(asp + ((unsigned)s << 3) + hoff);
    uint4 r = *(const uint4*)(hbp + ((unsigned)s << 8) + qoff);
    float m = __expf(leaky(e + ad_my));
    fma8(a, m, r);
    dpart += m;
  }

  // head swap within the 16-lane group (serves all 4 nodes of the wave)
  float b[8];
#pragma unroll
  for (int i = 0; i < 8; i++) b[i] = __shfl_xor(a[i], 8);
  float denO = __shfl_xor(dpart, 8);

  if (q < 8) {  // channels 8q..8q+7
    float rr0 = 1.f / (dpart + 1e-16f), rr1 = 1.f / (denO + 1e-16f);
    float4 bl = *(const float4*)&bias[q * 8];
    float4 bh = *(const float4*)&bias[q * 8 + 4];
    f32x4 o0, o1;
    o0.x = 0.5f * (a[0] * rr0 + b[0] * rr1) + bl.x;
    o0.y = 0.5f * (a[1] * rr0 + b[1] * rr1) + bl.y;
    o0.z = 0.5f * (a[2] * rr0 + b[2] * rr1) + bl.z;
    o0.w = 0.5f * (a[3] * rr0 + b[3] * rr1) + bl.w;
    o1.x = 0.5f * (a[4] * rr0 + b[4] * rr1) + bh.x;
    o1.y = 0.5f * (a[5] * rr0 + b[5] * rr1) + bh.y;
    o1.z = 0.5f * (a[6] * rr0 + b[6] * rr1) + bh.z;
    o1.w = 0.5f * (a[7] * rr0 + b[7] * rr1) + bh.w;
    f32x4* outp = (f32x4*)&out[(size_t)d * 64 + q * 8];
    __builtin_nontemporal_store(o0, outp);
    __builtin_nontemporal_store(o1, outp + 1);
  }
}

// ---------------- MLP head: fused tiled GEMM (64 nodes / block) --------------
// a1 staging applies BN(layer3 scsh)+ReLU to the raw aggregate output.
__global__ __launch_bounds__(256) void mlp_head_tiled(
    const float* __restrict__ h3raw, const float* __restrict__ scsh,
    const float* __restrict__ x,
    const float* __restrict__ mW1, const float* __restrict__ mb1,
    const float* __restrict__ mW2, const float* __restrict__ mb2,
    const float* __restrict__ pW, const float* __restrict__ pb,
    const float* __restrict__ vW, const float* __restrict__ vb,
    float* __restrict__ out, int n) {
  __shared__ float lds[13632];
  float* a1  = lds;           // 64*68 = 4352
  float* ctx = lds + 4352;    // 64*8  = 512
  float* a2  = lds + 4864;    // 64*68 = 4352
  float* w1  = lds + 9216;    // 69*64 = 4416
  float* w2  = lds;           // aliases a1 (dead after GEMM1)

  int t = threadIdx.x;
  int node0 = blockIdx.x * 64;
  int rows = min(64, n - node0);

#pragma unroll
  for (int i = 0; i < 4; i++) {
    int flat = t + i * 256;
    int r = flat >> 4, kc = flat & 15;
    float4 v = make_float4(0.f, 0.f, 0.f, 0.f);
    if (r < rows) v = *(const float4*)&h3raw[(size_t)(node0 + r) * 64 + kc * 4];
    float4 sc4 = *(const float4*)&scsh[kc * 4];
    float4 sh4 = *(const float4*)&scsh[64 + kc * 4];
    v.x = fmaxf(fmaf(v.x, sc4.x, sh4.x), 0.f);
    v.y = fmaxf(fmaf(v.y, sc4.y, sh4.y), 0.f);
    v.z = fmaxf(fmaf(v.z, sc4.z, sh4.z), 0.f);
    v.w = fmaxf(fmaf(v.w, sc4.w, sh4.w), 0.f);
    *(float4*)&a1[r * 68 + kc * 4] = v;
  }
  for (int i = t; i < 320; i += 256) {
    int r = i / 5, j = i % 5;
    ctx[r * 8 + j] = (r < rows) ? x[(size_t)(node0 + r) * 16 + 9 + j] : 0.f;
  }
#pragma unroll
  for (int i = 0; i < 5; i++) {
    int flat = t + i * 256;
    if (flat < 1104) *(float4*)&w1[flat * 4] = *(const float4*)&mW1[flat * 4];
  }
  __syncthreads();

  int tc = t & 15, tr = t >> 4;
  int c0 = tc * 4, r0 = tr * 4;

  float acc[4][4] = {};
  for (int k = 0; k < 64; k += 4) {
    float4 av[4], wv[4];
#pragma unroll
    for (int i = 0; i < 4; i++) av[i] = *(const float4*)&a1[(r0 + i) * 68 + k];
#pragma unroll
    for (int j = 0; j < 4; j++) wv[j] = *(const float4*)&w1[(k + j) * 64 + c0];
#pragma unroll
    for (int i = 0; i < 4; i++) {
      const float* ai = (const float*)&av[i];
#pragma unroll
      for (int kk = 0; kk < 4; kk++) {
        const float* wr = (const float*)&wv[kk];
        acc[i][0] = fmaf(ai[kk], wr[0], acc[i][0]);
        acc[i][1] = fmaf(ai[kk], wr[1], acc[i][1]);
        acc[i][2] = fmaf(ai[kk], wr[2], acc[i][2]);
        acc[i][3] = fmaf(ai[kk], wr[3], acc[i][3]);
      }
    }
  }
#pragma unroll
  for (int k = 64; k < 69; k++) {
    float4 wv = *(const float4*)&w1[k * 64 + c0];
    const float* wr = (const float*)&wv;
#pragma unroll
    for (int i = 0; i < 4; i++) {
      float a = ctx[(r0 + i) * 8 + (k - 64)];
      acc[i][0] = fmaf(a, wr[0], acc[i][0]);
      acc[i][1] = fmaf(a, wr[1], acc[i][1]);
      acc[i][2] = fmaf(a, wr[2], acc[i][2]);
      acc[i][3] = fmaf(a, wr[3], acc[i][3]);
    }
  }
  float b1v0 = mb1[c0], b1v1 = mb1[c0 + 1], b1v2 = mb1[c0 + 2], b1v3 = mb1[c0 + 3];
#pragma unroll
  for (int i = 0; i < 4; i++) {
    float4 t1;
    t1.x = fmaxf(acc[i][0] + b1v0, 0.f);
    t1.y = fmaxf(acc[i][1] + b1v1, 0.f);
    t1.z = fmaxf(acc[i][2] + b1v2, 0.f);
    t1.w = fmaxf(acc[i][3] + b1v3, 0.f);
    *(float4*)&a2[(r0 + i) * 68 + c0] = t1;
  }
  __syncthreads();

#pragma unroll
  for (int i = 0; i < 4; i++) {
    int flat = t + i * 256;
    *(float4*)&w2[flat * 4] = *(const float4*)&mW2[flat * 4];
  }
  __syncthreads();

  float acc2[4][4] = {};
  for (int k = 0; k < 64; k += 4) {
    float4 av[4], wv[4];
#pragma unroll
    for (int i = 0; i < 4; i++) av[i] = *(const float4*)&a2[(r0 + i) * 68 + k];
#pragma unroll
    for (int j = 0; j < 4; j++) wv[j] = *(const float4*)&w2[(k + j) * 64 + c0];
#pragma unroll
    for (int i = 0; i < 4; i++) {
      const float* ai = (const float*)&av[i];
#pragma unroll
      for (int kk = 0; kk < 4; kk++) {
        const float* wr = (const float*)&wv[kk];
        acc2[i][0] = fmaf(ai[kk], wr[0], acc2[i][0]);
        acc2[i][1] = fmaf(ai[kk], wr[1], acc2[i][1]);
        acc2[i][2] = fmaf(ai[kk], wr[2], acc2[i][2]);
        acc2[i][3] = fmaf(ai[kk], wr[3], acc2[i][3]);
      }
    }
  }

  float b2v[4], pwv[4], vwv[4];
#pragma unroll
  for (int j = 0; j < 4; j++) {
    b2v[j] = mb2[c0 + j];
    pwv[j] = pW[c0 + j];
    vwv[j] = vW[c0 + j];
  }
  float p[4], v[4];
#pragma unroll
  for (int i = 0; i < 4; i++) {
    float ps = 0.f, vs = 0.f;
#pragma unroll
    for (int j = 0; j < 4; j++) {
      float u = acc2[i][j] + b2v[j];
      ps = fmaf(u, pwv[j], ps);
      vs = fmaf(u, vwv[j], vs);
    }
    p[i] = ps; v[i] = vs;
  }
#pragma unroll
  for (int off = 1; off < 16; off <<= 1) {
#pragma unroll
    for (int i = 0; i < 4; i++) {
      p[i] += __shfl_xor(p[i], off);
      v[i] += __shfl_xor(v[i], off);
    }
  }
  if (tc == 0) {
    float pbs = pb[0], vbs = vb[0];
#pragma unroll
    for (int i = 0; i < 4; i++) {
      int r = r0 + i;
      if (r < rows) {
        out[node0 + r] = p[i] + pbs;
        out[n + node0 + r] = v[i] + vbs;
      }
    }
  }
}

extern "C" void kernel_launch(void* const* d_in, const int* in_sizes, int n_in,
                              void* d_out, int out_size, void* d_ws, size_t ws_size,
                              hipStream_t stream) {
  const float* x = (const float*)d_in[0];
  const int* ei = (const int*)d_in[1];
  const float* W[3]  = {(const float*)d_in[2],  (const float*)d_in[8],  (const float*)d_in[14]};
  const float* AS[3] = {(const float*)d_in[3],  (const float*)d_in[9],  (const float*)d_in[15]};
  const float* AD[3] = {(const float*)d_in[4],  (const float*)d_in[10], (const float*)d_in[16]};
  const float* B[3]  = {(const float*)d_in[5],  (const float*)d_in[11], (const float*)d_in[17]};
  const float* G[3]  = {(const float*)d_in[6],  (const float*)d_in[12], (const float*)d_in[18]};
  const float* BE[3] = {(const float*)d_in[7],  (const float*)d_in[13], (const float*)d_in[19]};
  const float* mW1 = (const float*)d_in[20];
  const float* mb1 = (const float*)d_in[21];
  const float* mW2 = (const float*)d_in[22];
  const float* mb2 = (const float*)d_in[23];
  const float* pW  = (const float*)d_in[24];
  const float* pb  = (const float*)d_in[25];
  const float* vW  = (const float*)d_in[26];
  const float* vb  = (const float*)d_in[27];

  const int N = in_sizes[0] / 16;
  const int E = in_sizes[1] / 2;
  const int* srcp = ei;
  const int* dstp = ei + E;

  // workspace carve-up (~65 MB)
  float* bufB  = (float*)d_ws;               // N*64  raw aggregate output
  float* hbuf  = bufB + (size_t)N * 64;      // N*64 half2 region (N*64 f32 bytes)
  float* as_   = hbuf + (size_t)N * 64;      // N*2
  float* ad_   = as_ + (size_t)N * 2;        // N*2
  float* stats = ad_ + (size_t)N * 2;        // NSL*128
  float* scsh  = stats + NSL * 128;          // 128
  int* row_ptr = (int*)(scsh + 128);         // N+1
  int* bcnt    = row_ptr + (N + 1);          // 512
  int* boff    = bcnt + 512;                 // 512
  int* bcur    = boff + 512;                 // 512
  int* col     = bcur + 512;                 // E ints (sorted CSR, src only)
  int2* ebuf   = (int2*)(col + E);           // E int2 (staging)
  __half2* hb  = (__half2*)hbuf;

  const int nbk = (N + 255) >> 8;
  const float inv_n = 1.0f / (float)N;

  // ---- CSR build: binned counting sort (R17 formulation)
  hipMemsetAsync(bcnt, 0, sizeof(int) * 512, stream);
  bucket_hist<<<256, 256, 0, stream>>>(dstp, bcnt, E);
  bucket_scan<<<1, 512, 0, stream>>>(bcnt, boff, bcur, nbk);
  bin_scatter<<<(E + 8191) / 8192, 256, 0, stream>>>(srcp, dstp, bcur, ebuf, E);
  bucket_sort<<<nbk, 256, 0, stream>>>(ebuf, boff, col, row_ptr, E, N, nbk);

  const int tiles = (N + 63) / 64;
  const int agg_blocks = (N + 15) / 16;  // 4 nodes/wave, 4 waves/block

  // ---- 3 GAT layers (BN+ReLU fused into the next consumer via scsh)
  for (int l = 0; l < 3; l++) {
    if (l == 0)
      gat_project_tiled<16, false><<<tiles, 256, 0, stream>>>(x, scsh, W[l], AS[l], AD[l],
                                                              hb, as_, ad_, N);
    else
      gat_project_tiled<64, true><<<tiles, 256, 0, stream>>>(bufB, scsh, W[l], AS[l], AD[l],
                                                             hb, as_, ad_, N);
    gat_aggregate<<<agg_blocks, 256, 0, stream>>>(hb, as_, ad_, row_ptr, col,
                                                  B[l], bufB, N);
    bn_stats<<<NSL, 256, 0, stream>>>(bufB, stats, N);
    bn_finalize<<<1, 128, 0, stream>>>(stats, G[l], BE[l], scsh, inv_n);
  }

  // ---- MLP head -> (logits, value); applies layer-3 BN+ReLU to bufB
  mlp_head_tiled<<<tiles, 256, 0, stream>>>(bufB, scsh, x, mW1, mb1, mW2, mb2,
                                            pW, pb, vW, vb, (float*)d_out, N);
}

// Round 8
// 471.527 us; speedup vs baseline: 1.0383x; 1.0383x over previous
//
#include <hip/hip_runtime.h>
#include <hip/hip_fp16.h>

// N=100000 nodes, E=1000000 edges, D_IN=16, H=2, C=64.
// 3x (GAT -> BN -> ReLU), then MLP head -> (logits, value) concat in d_out.
// R26: (a) aggregate reverted to exact R24 shape (R25's 8-deep unroll
// regressed: occ 63->41%, BW down); (b) projection rewritten on the MATRIX
// pipe: mfma_f32_16x16x32_f16, fp16 inputs (hb is already fp16 - same
// precision floor), fp32 accum. A/W staged to LDS fp16 with +8-half pad
// (odd 16B stride -> conflict-free b128 frag reads); att scores from C
// fragments via 16-lane xor-reduce; h via LDS re-tile -> coalesced 256B
// rows. K=16 zero-padded to 32 (one intrinsic everywhere).
// Kept: NT out stores, separate slice-write bn_stats (fused atomics cost
// ~50us, R22), R17 CSR build, scsh BN fusion into consumers.

__device__ __forceinline__ float leaky(float x) { return x > 0.f ? x : 0.2f * x; }

typedef float f32x4 __attribute__((ext_vector_type(4)));
typedef _Float16 f16x8 __attribute__((ext_vector_type(8)));

#define BCAP 4096  // max edges per 256-dst bucket (mean ~2560)
#define NSL 256    // bn_stats slices

// ---------------- CSR build ----------------
__global__ void bucket_hist(const int* __restrict__ dst, int* __restrict__ bcnt, int E) {
  __shared__ int cnt[512];
  int t = threadIdx.x;
  cnt[t] = 0; cnt[t + 256] = 0;
  __syncthreads();
  for (int e = blockIdx.x * blockDim.x + t; e < E; e += gridDim.x * blockDim.x)
    atomicAdd(&cnt[dst[e] >> 8], 1);
  __syncthreads();
  for (int i = t; i < 512; i += 256)
    if (cnt[i]) atomicAdd(&bcnt[i], cnt[i]);
}

__global__ void bucket_scan(const int* __restrict__ bcnt, int* __restrict__ boff,
                            int* __restrict__ bcur, int nbk) {
  __shared__ int temp[512];
  int t = threadIdx.x;  // 512 threads
  int v = (t < nbk) ? bcnt[t] : 0;
  temp[t] = v;
  __syncthreads();
  for (int off = 1; off < 512; off <<= 1) {
    int add = (t >= off) ? temp[t - off] : 0;
    __syncthreads();
    temp[t] += add;
    __syncthreads();
  }
  if (t < nbk) {
    int ex = temp[t] - v;
    boff[t] = ex;
    bcur[t] = ex;
  }
}

__global__ __launch_bounds__(256) void bin_scatter(
    const int* __restrict__ src, const int* __restrict__ dst,
    int* __restrict__ bcur, int2* __restrict__ ebuf, int E) {
  __shared__ int cnt[512];
  __shared__ int base[512];
  int t = threadIdx.x;
  int beg = blockIdx.x * 8192;
  int end = min(E, beg + 8192);
  cnt[t] = 0; cnt[t + 256] = 0;
  __syncthreads();
  for (int e = beg + t; e < end; e += 256)
    atomicAdd(&cnt[dst[e] >> 8], 1);
  __syncthreads();
  for (int i = t; i < 512; i += 256) {
    base[i] = cnt[i] ? atomicAdd(&bcur[i], cnt[i]) : 0;
    cnt[i] = 0;  // reuse as within-run cursor
  }
  __syncthreads();
  for (int e = beg + t; e < end; e += 256) {
    int d = dst[e];
    int bk = d >> 8;
    int off = atomicAdd(&cnt[bk], 1);
    ebuf[base[bk] + off] = make_int2(src[e], d);
  }
}

__global__ __launch_bounds__(256) void bucket_sort(
    const int2* __restrict__ ebuf, const int* __restrict__ boff,
    int* __restrict__ col, int* __restrict__ row_ptr, int E, int n, int nbk) {
  __shared__ int2 eds[BCAP];
  __shared__ int dcnt[256];
  __shared__ int dbase[256];
  __shared__ int dexcl[256];
  int b = blockIdx.x, t = threadIdx.x;
  int S = boff[b];
  int Eend = (b + 1 < nbk) ? boff[b + 1] : E;
  int cnt = min(Eend - S, BCAP);
  for (int i = t; i < cnt; i += 256) eds[i] = ebuf[S + i];
  dcnt[t] = 0;
  __syncthreads();
  for (int i = t; i < cnt; i += 256) atomicAdd(&dcnt[eds[i].y & 255], 1);
  __syncthreads();
  int v = dcnt[t];
  dbase[t] = v;
  __syncthreads();
  for (int off = 1; off < 256; off <<= 1) {
    int add = (t >= off) ? dbase[t - off] : 0;
    __syncthreads();
    dbase[t] += add;
    __syncthreads();
  }
  int excl = dbase[t] - v;
  int d = (b << 8) + t;
  if (d < n) row_ptr[d] = S + excl;
  if (b == nbk - 1 && t == 0) row_ptr[n] = E;
  dcnt[t] = 0;  // reuse as per-dst cursor
  dexcl[t] = excl;
  __syncthreads();
  for (int i = t; i < cnt; i += 256) {
    int2 e = eds[i];
    int dl = e.y & 255;
    int off = atomicAdd(&dcnt[dl], 1);
    col[S + dexcl[dl] + off] = e.x;
  }
}

// ---------------- BN stats (vectorized, slice writes) + finalize ----------
__global__ __launch_bounds__(256) void bn_stats(const float* __restrict__ h,
                                                float* __restrict__ stats, int n) {
  __shared__ float ssum[64], ssq[64];
  int t = threadIdx.x;
  if (t < 64) { ssum[t] = 0.f; ssq[t] = 0.f; }
  __syncthreads();
  const float4* h4 = (const float4*)h;
  size_t total4 = (size_t)n * 16;
  size_t stride = (size_t)gridDim.x * blockDim.x;   // multiple of 16
  int cbase = ((int)(((size_t)blockIdx.x * blockDim.x + t) & 15)) * 4;
  float s0 = 0.f, s1 = 0.f, s2 = 0.f, s3 = 0.f;
  float q0 = 0.f, q1 = 0.f, q2 = 0.f, q3 = 0.f;
  for (size_t i = (size_t)blockIdx.x * blockDim.x + t; i < total4; i += stride) {
    float4 v = h4[i];
    s0 += v.x; q0 = fmaf(v.x, v.x, q0);
    s1 += v.y; q1 = fmaf(v.y, v.y, q1);
    s2 += v.z; q2 = fmaf(v.z, v.z, q2);
    s3 += v.w; q3 = fmaf(v.w, v.w, q3);
  }
  atomicAdd(&ssum[cbase + 0], s0); atomicAdd(&ssq[cbase + 0], q0);
  atomicAdd(&ssum[cbase + 1], s1); atomicAdd(&ssq[cbase + 1], q1);
  atomicAdd(&ssum[cbase + 2], s2); atomicAdd(&ssq[cbase + 2], q2);
  atomicAdd(&ssum[cbase + 3], s3); atomicAdd(&ssq[cbase + 3], q3);
  __syncthreads();
  if (t < 64) {
    stats[blockIdx.x * 128 + t] = ssum[t];
    stats[blockIdx.x * 128 + 64 + t] = ssq[t];
  }
}

// reduce NSL slices -> scsh (scale/shift). 128 threads: t<64 sums, else sumsq.
__global__ void bn_finalize(const float* __restrict__ stats, const float* __restrict__ g,
                            const float* __restrict__ be, float* __restrict__ scsh,
                            float inv_n) {
  __shared__ float red[128];
  int t = threadIdx.x;  // 128
  int c = t & 63;
  int off = (t >> 6) * 64;  // 0 = sum, 64 = sumsq
  float acc = 0.f;
  for (int b = 0; b < NSL; b++) acc += stats[b * 128 + off + c];
  red[t] = acc;
  __syncthreads();
  if (t < 64) {
    float mean = red[t] * inv_n;
    float var = red[64 + t] * inv_n - mean * mean;
    float sc = rsqrtf(var + 1e-5f) * g[t];
    scsh[t] = sc;
    scsh[64 + t] = be[t] - mean * sc;
  }
}

// ---------------- GAT projection: MFMA fp16, 64 nodes x 128 cols ------------
// h = act @ W on the matrix pipe. 4 waves; wave w owns node rows w*16..+15,
// all 8 col-tiles. A[64][KP] and W^T[128][KP] staged fp16 in LDS, KP = KE+8
// (odd 16B stride -> conflict-free ds_read_b128 fragments). K=16 zero-padded
// to KE=32. C/D layout (m89): col=lane&15, row=(lane>>4)*4+reg.
template <int K, bool BN>
__global__ __launch_bounds__(256) void gat_project_mfma(
    const float* __restrict__ act, const float* __restrict__ scsh,
    const float* __restrict__ W,
    const float* __restrict__ att_s, const float* __restrict__ att_d,
    __half2* __restrict__ hb, float* __restrict__ as_,
    float* __restrict__ ad_, int n) {
  constexpr int KE = (K < 32) ? 32 : K;   // effective (padded) K
  constexpr int KP = KE + 8;              // LDS stride in halves
  constexpr int STAGE = 64 * KP * 2 + 128 * KP * 2;
  constexpr int HSZ = 64 * 136 * 2;
  constexpr int LDSZ = (STAGE > HSZ) ? STAGE : HSZ;
  __shared__ __align__(16) char ldsb[LDSZ];
  __shared__ float attS[256];
  __half* aH = (__half*)ldsb;                      // [64][KP]
  __half* wT = (__half*)(ldsb + 64 * KP * 2);      // [128][KP] (transposed W)
  __half* hS = (__half*)ldsb;                      // [64][136], aliases after barrier

  int t = threadIdx.x;
  int node0 = blockIdx.x * 64;
  int rows = min(64, n - node0);

  // ---- stage A: fp32 -> fp16, BN+ReLU fused; zero-pad r>=rows and k>=K
  constexpr int ACH = 64 * KE / 4;
  for (int i = t; i < ACH; i += 256) {
    int r = i / (KE / 4), kc = i % (KE / 4);
    float4 v = make_float4(0.f, 0.f, 0.f, 0.f);
    if (r < rows && kc * 4 < K)
      v = *(const float4*)&act[(size_t)(node0 + r) * K + kc * 4];
    if (BN) {
      float4 sc4 = *(const float4*)&scsh[kc * 4];
      float4 sh4 = *(const float4*)&scsh[64 + kc * 4];
      v.x = fmaxf(fmaf(v.x, sc4.x, sh4.x), 0.f);
      v.y = fmaxf(fmaf(v.y, sc4.y, sh4.y), 0.f);
      v.z = fmaxf(fmaf(v.z, sc4.z, sh4.z), 0.f);
      v.w = fmaxf(fmaf(v.w, sc4.w, sh4.w), 0.f);
    }
    __half2 h01 = __floats2half2_rn(v.x, v.y);
    __half2 h23 = __floats2half2_rn(v.z, v.w);
    uint2 pk = make_uint2(__builtin_bit_cast(unsigned, h01),
                          __builtin_bit_cast(unsigned, h23));
    *(uint2*)&aH[r * KP + kc * 4] = pk;
  }
  // ---- stage W^T: wT[c][k] fp16 (coalesced global read)
  for (int i = t; i < KE * 128; i += 256) {
    int k = i >> 7, c = i & 127;
    float wv = (k < K) ? W[k * 128 + c] : 0.f;
    wT[c * KP + k] = __float2half(wv);
  }
  attS[t] = (t < 128) ? att_s[t] : att_d[t - 128];
  __syncthreads();

  int w = t >> 6, l = t & 63;
  int cl = l & 15, r4 = l >> 4;
  int w16 = w * 16;

  f32x4 acc[8] = {};
#pragma unroll
  for (int ks = 0; ks < KE / 32; ks++) {
    f16x8 av = *(const f16x8*)&aH[(w16 + cl) * KP + ks * 32 + r4 * 8];
#pragma unroll
    for (int ct = 0; ct < 8; ct++) {
      f16x8 bv = *(const f16x8*)&wT[(ct * 16 + cl) * KP + ks * 32 + r4 * 8];
      acc[ct] = __builtin_amdgcn_mfma_f32_16x16x32_f16(av, bv, acc[ct], 0, 0, 0);
    }
  }

  // ---- att scores from accumulators (per-row dot with att vectors)
  float ats[8], atd[8];
#pragma unroll
  for (int ct = 0; ct < 8; ct++) {
    ats[ct] = attS[ct * 16 + cl];
    atd[ct] = attS[128 + ct * 16 + cl];
  }
#pragma unroll
  for (int i = 0; i < 4; i++) {
    float s0 = 0.f, s1 = 0.f, d0 = 0.f, d1 = 0.f;
#pragma unroll
    for (int ct = 0; ct < 4; ct++) {
      s0 = fmaf(acc[ct][i], ats[ct], s0);
      d0 = fmaf(acc[ct][i], atd[ct], d0);
      s1 = fmaf(acc[ct + 4][i], ats[ct + 4], s1);
      d1 = fmaf(acc[ct + 4][i], atd[ct + 4], d1);
    }
#pragma unroll
    for (int off = 1; off < 16; off <<= 1) {
      s0 += __shfl_xor(s0, off); s1 += __shfl_xor(s1, off);
      d0 += __shfl_xor(d0, off); d1 += __shfl_xor(d1, off);
    }
    int rloc = w16 + r4 * 4 + i;
    if (rloc < rows) {
      int row = node0 + rloc;
      if (cl == 0) as_[row * 2] = s0;
      else if (cl == 1) as_[row * 2 + 1] = s1;
      else if (cl == 2) ad_[row * 2] = d0;
      else if (cl == 3) ad_[row * 2 + 1] = d1;
    }
  }

  __syncthreads();  // aH/wT dead -> reuse as hS
  // ---- C fragments -> hS fp16 [64][136]
#pragma unroll
  for (int ct = 0; ct < 8; ct++)
#pragma unroll
    for (int i = 0; i < 4; i++)
      hS[(w16 + r4 * 4 + i) * 136 + ct * 16 + cl] = __float2half(acc[ct][i]);
  __syncthreads();
  // ---- hS -> hb, coalesced 16B chunks (256B per node row)
#pragma unroll
  for (int it = 0; it < 4; it++) {
    int flat = t + it * 256;
    int nd = flat >> 4, ch = flat & 15;
    if (nd < rows)
      *(uint4*)((char*)hb + (((size_t)(node0 + nd)) << 8) + (ch << 4)) =
          *(const uint4*)((const char*)hS + nd * 272 + (ch << 4));
  }
}

// ---------------- GAT aggregation: 16 lanes/node, 4 nodes/wave (R24) --------
// Lane q of a 16-lane group accumulates channels 8(q&7)..8(q&7)+7 of head
// (q>=8) over ALL edges of its node. 4-deep unroll = 4 independent 256B hb
// rows in flight per group. den accumulated redundantly per lane. Epilogue:
// 9-op shfl_xor(8) head-swap serving 4 nodes at once. NT out stores.
__device__ __forceinline__ void fma8(float* a, float my, uint4 raw) {
  float2 f;
  f = __half22float2(__builtin_bit_cast(__half2, raw.x)); a[0] = fmaf(my, f.x, a[0]); a[1] = fmaf(my, f.y, a[1]);
  f = __half22float2(__builtin_bit_cast(__half2, raw.y)); a[2] = fmaf(my, f.x, a[2]); a[3] = fmaf(my, f.y, a[3]);
  f = __half22float2(__builtin_bit_cast(__half2, raw.z)); a[4] = fmaf(my, f.x, a[4]); a[5] = fmaf(my, f.y, a[5]);
  f = __half22float2(__builtin_bit_cast(__half2, raw.w)); a[6] = fmaf(my, f.x, a[6]); a[7] = fmaf(my, f.y, a[7]);
}

__global__ __launch_bounds__(256) void gat_aggregate(
    const __half2* __restrict__ hb,
    const float* __restrict__ as_, const float* __restrict__ ad_,
    const int* __restrict__ row_ptr, const int* __restrict__ col,
    const float* __restrict__ bias, float* __restrict__ out, int n) {
  int w = (int)((blockIdx.x * blockDim.x + threadIdx.x) >> 6);
  int lane = threadIdx.x & 63;
  int g = lane >> 4, q = lane & 15;
  int d = w * 4 + g;
  if (d >= n) return;  // diverges only in the last wave
  int hidx = (q >= 8) ? 1 : 0;
  int beg = row_ptr[d], end = row_ptr[d + 1];
  const uint4* hb4 = (const uint4*)hb;   // 16 uint4 per node (256 B)

  float ad_my = ad_[d * 2 + hidx];

  float a[8] = {};
  // self-loop (not in CSR)
  float asv = as_[d * 2 + hidx];
  float my = __expf(leaky(asv + ad_my));
  uint4 raw = hb4[(size_t)d * 16 + q];
  fma8(a, my, raw);
  float dpart = my;

  int k = beg;
  for (; k + 3 < end; k += 4) {
    int s0 = col[k], s1 = col[k + 1], s2 = col[k + 2], s3 = col[k + 3];
    float e0 = as_[s0 * 2 + hidx];
    float e1 = as_[s1 * 2 + hidx];
    float e2 = as_[s2 * 2 + hidx];
    float e3 = as_[s3 * 2 + hidx];
    uint4 r0 = hb4[(size_t)s0 * 16 + q];
    uint4 r1 = hb4[(size_t)s1 * 16 + q];
    uint4 r2 = hb4[(size_t)s2 * 16 + q];
    uint4 r3 = hb4[(size_t)s3 * 16 + q];
    float m0 = __expf(leaky(e0 + ad_my));
    float m1 = __expf(leaky(e1 + ad_my));
    float m2 = __expf(leaky(e2 + ad_my));
    float m3 = __expf(leaky(e3 + ad_my));
    fma8(a, m0, r0); fma8(a, m1, r1); fma8(a, m2, r2); fma8(a, m3, r3);
    dpart += m0 + m1 + m2 + m3;
  }
  for (; k < end; k++) {  // tail 0..3
    int s = col[k];
    float e = as_[s * 2 + hidx];
    uint4 r = hb4[(size_t)s * 16 + q];
    float m = __expf(leaky(e + ad_my));
    fma8(a, m, r);
    dpart += m;
  }

  // head swap within the 16-lane group (serves all 4 nodes of the wave)
  float b[8];
#pragma unroll
  for (int i = 0; i < 8; i++) b[i] = __shfl_xor(a[i], 8);
  float denO = __shfl_xor(dpart, 8);

  if (q < 8) {  // channels 8q..8q+7
    float rr0 = 1.f / (dpart + 1e-16f), rr1 = 1.f / (denO + 1e-16f);
    float4 bl = *(const float4*)&bias[q * 8];
    float4 bh = *(const float4*)&bias[q * 8 + 4];
    f32x4 o0, o1;
    o0.x = 0.5f * (a[0] * rr0 + b[0] * rr1) + bl.x;
    o0.y = 0.5f * (a[1] * rr0 + b[1] * rr1) + bl.y;
    o0.z = 0.5f * (a[2] * rr0 + b[2] * rr1) + bl.z;
    o0.w = 0.5f * (a[3] * rr0 + b[3] * rr1) + bl.w;
    o1.x = 0.5f * (a[4] * rr0 + b[4] * rr1) + bh.x;
    o1.y = 0.5f * (a[5] * rr0 + b[5] * rr1) + bh.y;
    o1.z = 0.5f * (a[6] * rr0 + b[6] * rr1) + bh.z;
    o1.w = 0.5f * (a[7] * rr0 + b[7] * rr1) + bh.w;
    f32x4* outp = (f32x4*)&out[(size_t)d * 64 + q * 8];
    __builtin_nontemporal_store(o0, outp);
    __builtin_nontemporal_store(o1, outp + 1);
  }
}

// ---------------- MLP head: fused tiled GEMM (64 nodes / block) --------------
// a1 staging applies BN(layer3 scsh)+ReLU to the raw aggregate output.
__global__ __launch_bounds__(256) void mlp_head_tiled(
    const float* __restrict__ h3raw, const float* __restrict__ scsh,
    const float* __restrict__ x,
    const float* __restrict__ mW1, const float* __restrict__ mb1,
    const float* __restrict__ mW2, const float* __restrict__ mb2,
    const float* __restrict__ pW, const float* __restrict__ pb,
    const float* __restrict__ vW, const float* __restrict__ vb,
    float* __restrict__ out, int n) {
  __shared__ float lds[13632];
  float* a1  = lds;           // 64*68 = 4352
  float* ctx = lds + 4352;    // 64*8  = 512
  float* a2  = lds + 4864;    // 64*68 = 4352
  float* w1  = lds + 9216;    // 69*64 = 4416
  float* w2  = lds;           // aliases a1 (dead after GEMM1)

  int t = threadIdx.x;
  int node0 = blockIdx.x * 64;
  int rows = min(64, n - node0);

#pragma unroll
  for (int i = 0; i < 4; i++) {
    int flat = t + i * 256;
    int r = flat >> 4, kc = flat & 15;
    float4 v = make_float4(0.f, 0.f, 0.f, 0.f);
    if (r < rows) v = *(const float4*)&h3raw[(size_t)(node0 + r) * 64 + kc * 4];
    float4 sc4 = *(const float4*)&scsh[kc * 4];
    float4 sh4 = *(const float4*)&scsh[64 + kc * 4];
    v.x = fmaxf(fmaf(v.x, sc4.x, sh4.x), 0.f);
    v.y = fmaxf(fmaf(v.y, sc4.y, sh4.y), 0.f);
    v.z = fmaxf(fmaf(v.z, sc4.z, sh4.z), 0.f);
    v.w = fmaxf(fmaf(v.w, sc4.w, sh4.w), 0.f);
    *(float4*)&a1[r * 68 + kc * 4] = v;
  }
  for (int i = t; i < 320; i += 256) {
    int r = i / 5, j = i % 5;
    ctx[r * 8 + j] = (r < rows) ? x[(size_t)(node0 + r) * 16 + 9 + j] : 0.f;
  }
#pragma unroll
  for (int i = 0; i < 5; i++) {
    int flat = t + i * 256;
    if (flat < 1104) *(float4*)&w1[flat * 4] = *(const float4*)&mW1[flat * 4];
  }
  __syncthreads();

  int tc = t & 15, tr = t >> 4;
  int c0 = tc * 4, r0 = tr * 4;

  float acc[4][4] = {};
  for (int k = 0; k < 64; k += 4) {
    float4 av[4], wv[4];
#pragma unroll
    for (int i = 0; i < 4; i++) av[i] = *(const float4*)&a1[(r0 + i) * 68 + k];
#pragma unroll
    for (int j = 0; j < 4; j++) wv[j] = *(const float4*)&w1[(k + j) * 64 + c0];
#pragma unroll
    for (int i = 0; i < 4; i++) {
      const float* ai = (const float*)&av[i];
#pragma unroll
      for (int kk = 0; kk < 4; kk++) {
        const float* wr = (const float*)&wv[kk];
        acc[i][0] = fmaf(ai[kk], wr[0], acc[i][0]);
        acc[i][1] = fmaf(ai[kk], wr[1], acc[i][1]);
        acc[i][2] = fmaf(ai[kk], wr[2], acc[i][2]);
        acc[i][3] = fmaf(ai[kk], wr[3], acc[i][3]);
      }
    }
  }
#pragma unroll
  for (int k = 64; k < 69; k++) {
    float4 wv = *(const float4*)&w1[k * 64 + c0];
    const float* wr = (const float*)&wv;
#pragma unroll
    for (int i = 0; i < 4; i++) {
      float a = ctx[(r0 + i) * 8 + (k - 64)];
      acc[i][0] = fmaf(a, wr[0], acc[i][0]);
      acc[i][1] = fmaf(a, wr[1], acc[i][1]);
      acc[i][2] = fmaf(a, wr[2], acc[i][2]);
      acc[i][3] = fmaf(a, wr[3], acc[i][3]);
    }
  }
  float b1v0 = mb1[c0], b1v1 = mb1[c0 + 1], b1v2 = mb1[c0 + 2], b1v3 = mb1[c0 + 3];
#pragma unroll
  for (int i = 0; i < 4; i++) {
    float4 t1;
    t1.x = fmaxf(acc[i][0] + b1v0, 0.f);
    t1.y = fmaxf(acc[i][1] + b1v1, 0.f);
    t1.z = fmaxf(acc[i][2] + b1v2, 0.f);
    t1.w = fmaxf(acc[i][3] + b1v3, 0.f);
    *(float4*)&a2[(r0 + i) * 68 + c0] = t1;
  }
  __syncthreads();

#pragma unroll
  for (int i = 0; i < 4; i++) {
    int flat = t + i * 256;
    *(float4*)&w2[flat * 4] = *(const float4*)&mW2[flat * 4];
  }
  __syncthreads();

  float acc2[4][4] = {};
  for (int k = 0; k < 64; k += 4) {
    float4 av[4], wv[4];
#pragma unroll
    for (int i = 0; i < 4; i++) av[i] = *(const float4*)&a2[(r0 + i) * 68 + k];
#pragma unroll
    for (int j = 0; j < 4; j++) wv[j] = *(const float4*)&w2[(k + j) * 64 + c0];
#pragma unroll
    for (int i = 0; i < 4; i++) {
      const float* ai = (const float*)&av[i];
#pragma unroll
      for (int kk = 0; kk < 4; kk++) {
        const float* wr = (const float*)&wv[kk];
        acc2[i][0] = fmaf(ai[kk], wr[0], acc2[i][0]);
        acc2[i][1] = fmaf(ai[kk], wr[1], acc2[i][1]);
        acc2[i][2] = fmaf(ai[kk], wr[2], acc2[i][2]);
        acc2[i][3] = fmaf(ai[kk], wr[3], acc2[i][3]);
      }
    }
  }

  float b2v[4], pwv[4], vwv[4];
#pragma unroll
  for (int j = 0; j < 4; j++) {
    b2v[j] = mb2[c0 + j];
    pwv[j] = pW[c0 + j];
    vwv[j] = vW[c0 + j];
  }
  float p[4], v[4];
#pragma unroll
  for (int i = 0; i < 4; i++) {
    float ps = 0.f, vs = 0.f;
#pragma unroll
    for (int j = 0; j < 4; j++) {
      float u = acc2[i][j] + b2v[j];
      ps = fmaf(u, pwv[j], ps);
      vs = fmaf(u, vwv[j], vs);
    }
    p[i] = ps; v[i] = vs;
  }
#pragma unroll
  for (int off = 1; off < 16; off <<= 1) {
#pragma unroll
    for (int i = 0; i < 4; i++) {
      p[i] += __shfl_xor(p[i], off);
      v[i] += __shfl_xor(v[i], off);
    }
  }
  if (tc == 0) {
    float pbs = pb[0], vbs = vb[0];
#pragma unroll
    for (int i = 0; i < 4; i++) {
      int r = r0 + i;
      if (r < rows) {
        out[node0 + r] = p[i] + pbs;
        out[n + node0 + r] = v[i] + vbs;
      }
    }
  }
}

extern "C" void kernel_launch(void* const* d_in, const int* in_sizes, int n_in,
                              void* d_out, int out_size, void* d_ws, size_t ws_size,
                              hipStream_t stream) {
  const float* x = (const float*)d_in[0];
  const int* ei = (const int*)d_in[1];
  const float* W[3]  = {(const float*)d_in[2],  (const float*)d_in[8],  (const float*)d_in[14]};
  const float* AS[3] = {(const float*)d_in[3],  (const float*)d_in[9],  (const float*)d_in[15]};
  const float* AD[3] = {(const float*)d_in[4],  (const float*)d_in[10], (const float*)d_in[16]};
  const float* B[3]  = {(const float*)d_in[5],  (const float*)d_in[11], (const float*)d_in[17]};
  const float* G[3]  = {(const float*)d_in[6],  (const float*)d_in[12], (const float*)d_in[18]};
  const float* BE[3] = {(const float*)d_in[7],  (const float*)d_in[13], (const float*)d_in[19]};
  const float* mW1 = (const float*)d_in[20];
  const float* mb1 = (const float*)d_in[21];
  const float* mW2 = (const float*)d_in[22];
  const float* mb2 = (const float*)d_in[23];
  const float* pW  = (const float*)d_in[24];
  const float* pb  = (const float*)d_in[25];
  const float* vW  = (const float*)d_in[26];
  const float* vb  = (const float*)d_in[27];

  const int N = in_sizes[0] / 16;
  const int E = in_sizes[1] / 2;
  const int* srcp = ei;
  const int* dstp = ei + E;

  // workspace carve-up (~65 MB)
  float* bufB  = (float*)d_ws;               // N*64  raw aggregate output
  float* hbuf  = bufB + (size_t)N * 64;      // N*64 half2 region (N*64 f32 bytes)
  float* as_   = hbuf + (size_t)N * 64;      // N*2
  float* ad_   = as_ + (size_t)N * 2;        // N*2
  float* stats = ad_ + (size_t)N * 2;        // NSL*128
  float* scsh  = stats + NSL * 128;          // 128
  int* row_ptr = (int*)(scsh + 128);         // N+1
  int* bcnt    = row_ptr + (N + 1);          // 512
  int* boff    = bcnt + 512;                 // 512
  int* bcur    = boff + 512;                 // 512
  int* col     = bcur + 512;                 // E ints (sorted CSR, src only)
  int2* ebuf   = (int2*)(col + E);           // E int2 (staging)
  __half2* hb  = (__half2*)hbuf;

  const int nbk = (N + 255) >> 8;
  const float inv_n = 1.0f / (float)N;

  // ---- CSR build: binned counting sort (R17 formulation)
  hipMemsetAsync(bcnt, 0, sizeof(int) * 512, stream);
  bucket_hist<<<256, 256, 0, stream>>>(dstp, bcnt, E);
  bucket_scan<<<1, 512, 0, stream>>>(bcnt, boff, bcur, nbk);
  bin_scatter<<<(E + 8191) / 8192, 256, 0, stream>>>(srcp, dstp, bcur, ebuf, E);
  bucket_sort<<<nbk, 256, 0, stream>>>(ebuf, boff, col, row_ptr, E, N, nbk);

  const int tiles = (N + 63) / 64;
  const int agg_blocks = (N + 15) / 16;  // 4 nodes/wave, 4 waves/block

  // ---- 3 GAT layers (BN+ReLU fused into the next consumer via scsh)
  for (int l = 0; l < 3; l++) {
    if (l == 0)
      gat_project_mfma<16, false><<<tiles, 256, 0, stream>>>(x, scsh, W[l], AS[l], AD[l],
                                                             hb, as_, ad_, N);
    else
      gat_project_mfma<64, true><<<tiles, 256, 0, stream>>>(bufB, scsh, W[l], AS[l], AD[l],
                                                            hb, as_, ad_, N);
    gat_aggregate<<<agg_blocks, 256, 0, stream>>>(hb, as_, ad_, row_ptr, col,
                                                  B[l], bufB, N);
    bn_stats<<<NSL, 256, 0, stream>>>(bufB, stats, N);
    bn_finalize<<<1, 128, 0, stream>>>(stats, G[l], BE[l], scsh, inv_n);
  }

  // ---- MLP head -> (logits, value); applies layer-3 BN+ReLU to bufB
  mlp_head_tiled<<<tiles, 256, 0, stream>>>(bufB, scsh, x, mW1, mb1, mW2, mb2,
                                            pW, pb, vW, vb, (float*)d_out, N);
}